// Round 9
// baseline (220.169 us; speedup 1.0000x reference)
//
#include <hip/hip_runtime.h>

// NonZeroFeatureExtractor — DIAGNOSTIC ROUND: R8 kernel body byte-identical,
// but grid.z doubled (each tile computed twice, identical writes -> benign,
// correctness-preserving). Purpose: push dispatch past the 150us harness
// fills so OUR counters (VALUBusy / Occupancy / LDS_BANK_CONFLICT /
// FETCH / WRITE) finally appear in the top-5 table — first real counter
// read since R2. Pre-committed interpretation in the session journal.
//
// Kernel: pair-packed ring, compile-time geometry (R8, 110.9us single):
//   ringL32[pair][col] = (lumQpref[odd]<<16) | lumQpref[even]  (u16 wrap, x1024 RNE)
//   ringN16[pair][col] = (nzpref[odd]<<8)   | nzpref[even]     (u8 mod 256)
// 19 pair-slots = 29.3 KB -> 5 blocks/CU x 4 waves = 20 waves/CU.

constexpr int THREADS = 256;
constexpr int LOADW   = 256;
constexpr int HALO    = 17;
constexpr int COUT    = 223;   // LOADW - 33
constexpr int RING2   = 19;    // pair-rows: 18 read slots + 1 write slot
constexpr int ROWSEG  = 32;

constexpr int    Wc  = 1024;
constexpr int    Hc  = 1024;
constexpr size_t HWc = (size_t)Hc * Wc;

__device__ __forceinline__ void barrier_lds() {
    asm volatile("s_waitcnt lgkmcnt(0)" ::: "memory");
    __builtin_amdgcn_s_barrier();
    __builtin_amdgcn_sched_barrier(0);
}

template<int CTRL, int RM>
__device__ __forceinline__ int dppadd_i(int v) {
    int sh = __builtin_amdgcn_update_dpp(0, v, CTRL, RM, 0xF, true);
    return v + sh;
}

// 64-lane inclusive scan over int, pure VALU (validated R3-R8)
__device__ __forceinline__ int wave_iscan_i(int v) {
    v = dppadd_i<0x111, 0xF>(v);
    v = dppadd_i<0x112, 0xF>(v);
    v = dppadd_i<0x114, 0xF>(v);
    v = dppadd_i<0x118, 0xF>(v);
    v = dppadd_i<0x142, 0xA>(v);   // ROW_BCAST15 -> rows 1,3
    v = dppadd_i<0x143, 0xC>(v);   // ROW_BCAST31 -> rows 2,3
    return v;
}

__device__ __forceinline__ int sx16(unsigned v) {
    return (int)(short)(unsigned short)v;
}

__global__ __launch_bounds__(THREADS, 5)
void nzfeat_kernel(const float* __restrict__ x, float* __restrict__ out, int B) {
    constexpr int   PP[4]   = {1, 4, 8, 16};
    constexpr float INVA[4] = {1.f/9.f, 1.f/81.f, 1.f/289.f, 1.f/1089.f};
    constexpr float INVQ    = 1.f / 1024.f;

    __shared__ unsigned int   ringL[RING2][LOADW];  // pair-packed lum prefixes
    __shared__ unsigned short ringN[RING2][LOADW];  // pair-packed nz prefixes
    __shared__ int2           wsum[2][2][4];        // [parity][row][wave]

    const int t    = threadIdx.x;
    const int lane = t & 63;
    const int wv   = t >> 6;

    const int x0 = blockIdx.x * COUT;
    const int y0 = blockIdx.y * ROWSEG;   // multiple of 32 -> even
    const int bz = blockIdx.z;
    const int b  = (bz < B) ? bz : bz - B;   // DIAG: second generation redoes batch

    const int    gx   = x0 - HALO + t;
    const bool   gxok = (gx >= 0) && (gx < Wc);
    const int    gxc  = min(max(gx, 0), Wc - 1);
    const float* xb   = x + (size_t)b * 3 * HWc + gxc;

    auto load_row = [&](int r, float& a0, float& a1, float& a2) {
        const int rc = min(max(r, 0), Hc - 1);
        const float* p = xb + ((size_t)rc << 10);   // rc * Wc
        a0 = p[0]; a1 = p[HWc]; a2 = p[2 * HWc];
    };

    // pair-slot of pair-index j (j = row >> 1); +190 = 10*19 keeps it >= 0
    auto ps2  = [&](int j) { return (int)((unsigned)(j + 190) % (unsigned)RING2); };
    auto wpos = [&](int v) { return v >= RING2 ? v - RING2 : v; };
    auto wneg = [&](int v) { return v < 0 ? v + RING2 : v; };

    // per-wave-segment inclusive prefixes; lane 63 posts wave totals
    auto scan_local = [&](float c0, float c1, float c2, int r, int par, int which) -> int2 {
        float lum = 0.f;
        if (gxok && (unsigned)r < (unsigned)Hc)
            lum = (c0 + c1 + c2) * (1.0f / 3.0f);
        const bool nzb = (lum != 0.f);
        unsigned long long m = __ballot(nzb);
        int below = __builtin_amdgcn_mbcnt_hi((unsigned)(m >> 32),
                      __builtin_amdgcn_mbcnt_lo((unsigned)m, 0));
        int np = below + (nzb ? 1 : 0);
        int q  = (int)rintf(lum * 1024.f);
        int lp = wave_iscan_i(q);
        if (lane == 63) wsum[par][which][wv] = make_int2(lp, np);
        return make_int2(lp, np);
    };

    // add lower-wave totals, pack even(A)/odd(Bv) rows into one word each
    auto combine_write = [&](int par, int2 A, int2 Bv, int pslot) {
        int oAl = 0, oAn = 0, oBl = 0, oBn = 0;
        #pragma unroll
        for (int w2 = 0; w2 < 3; ++w2)
            if (w2 < wv) {
                int2 u = wsum[par][0][w2]; int2 v = wsum[par][1][w2];
                oAl += u.x; oAn += u.y; oBl += v.x; oBn += v.y;
            }
        unsigned llo = (unsigned)(A.x + oAl) & 0xFFFFu;
        unsigned lhi = (unsigned)(Bv.x + oBl) & 0xFFFFu;
        ringL[pslot][t] = (lhi << 16) | llo;
        unsigned nlo = (unsigned)(A.y + oAn) & 0xFFu;
        unsigned nhi = (unsigned)(Bv.y + oBn) & 0xFFu;
        ringN[pslot][t] = (unsigned short)((nhi << 8) | nlo);
    };

    // window diffs of BOTH rows of an aligned pair at slot s
    auto rdAligned = [&](int s, int x1, int d, int& dl0, int& dl1,
                         int& dn0, int& dn1) {
        const unsigned int* Lp = &ringL[s][x1];
        unsigned w0 = Lp[0], w1 = Lp[d];
        dl0 = sx16(w1 - w0);
        dl1 = sx16((w1 >> 16) - (w0 >> 16));
        const unsigned short* Np = &ringN[s][x1];
        unsigned n0 = Np[0], n1 = Np[d];
        dn0 = (int)((n1 - n0) & 0xFFu);
        dn1 = (int)(((n1 >> 8) - (n0 >> 8)) & 0xFFu);
    };
    // rows straddling two pairs: A = hi field of sH, B = lo field of sL2
    auto rdStraddle = [&](int sH, int sL2, int x1, int d, int& dA, int& dB,
                          int& nA, int& nB) {
        const unsigned int* LpH = &ringL[sH][x1];
        unsigned h0 = LpH[0], h1 = LpH[d];
        dA = sx16((h1 >> 16) - (h0 >> 16));
        const unsigned int* LpL = &ringL[sL2][x1];
        unsigned l0 = LpL[0], l1 = LpL[d];
        dB = sx16(l1 - l0);
        const unsigned short* NpH = &ringN[sH][x1];
        unsigned m0 = NpH[0], m1 = NpH[d];
        nA = (int)(((m1 >> 8) - (m0 >> 8)) & 0xFFu);
        const unsigned short* NpL = &ringN[sL2][x1];
        unsigned k0 = NpL[0], k1 = NpL[d];
        nB = (int)((k1 - k0) & 0xFFu);
    };

    // ---- prologue: scan rows [y0-18, y0+15] in 17 pair-iterations ----
    float a0, a1, a2, b0c, b1c, b2c;
    load_row(y0 - 18, a0, a1, a2);
    load_row(y0 - 17, b0c, b1c, b2c);
    for (int i = 0; i < 17; ++i) {
        const int rA = y0 - 18 + 2 * i;          // even
        float n0, n1, n2, m0, m1, m2;
        load_row(rA + 2, n0, n1, n2);
        load_row(rA + 3, m0, m1, m2);
        int2 A  = scan_local(a0, a1, a2, rA, i & 1, 0);
        int2 Bv = scan_local(b0c, b1c, b2c, rA + 1, i & 1, 1);
        barrier_lds();
        combine_write(i & 1, A, Bv, ps2(rA >> 1));
        a0 = n0; a1 = n1; a2 = n2; b0c = m0; b1c = m1; b2c = m2;
    }
    // regs hold rows y0+16, y0+17
    barrier_lds();   // prologue writes visible before priming reads

    const bool activeCol = (t < COUT) && (x0 + t < Wc);
    const int  tx = min(t, COUT - 1);            // clamp keeps LDS reads in-bounds
    float* outb = out + (size_t)b * 8 * HWc + (x0 + t);

    // ---- prime vertical sums (i32) for virtual row y0-1 ----
    int vl[4], vn[4];
    #pragma unroll
    for (int i = 0; i < 4; ++i) {
        const int p  = PP[i];
        const int d  = 2 * p + 1;
        const int x1 = tx + HALO - p - 1;
        int sl = 0, sn = 0;
        for (int rr = y0 - 1 - p; rr <= y0 - 1 + p; ++rr) {
            const int s = ps2(rr >> 1);
            const unsigned int* Lp = &ringL[s][x1];
            unsigned w0 = Lp[0], w1 = Lp[d];
            const unsigned short* Np = &ringN[s][x1];
            unsigned n0 = Np[0], n1 = Np[d];
            if (rr & 1) {
                sl += sx16((w1 >> 16) - (w0 >> 16));
                sn += (int)(((n1 >> 8) - (n0 >> 8)) & 0xFFu);
            } else {
                sl += sx16(w1 - w0);
                sn += (int)((n1 - n0) & 0xFFu);
            }
        }
        vl[i] = sl; vn[i] = sn;
    }

    // ---- main: 17 iterations. Scan rows y0+2k+16,17 (k<16); emit pair
    //      ye = y0+2(k-1) (k>=1). ONE barrier/iter. ----
    int pc = ps2(y0 >> 1);            // emit pair cursor (used from k=1)
    int pw = ps2((y0 >> 1) + 8);      // write pair slot at k=0
    for (int k = 0; k <= ROWSEG / 2; ++k) {
        const bool doScan = (k < ROWSEG / 2);
        int2 A = make_int2(0, 0), Bv = make_int2(0, 0);
        float n0 = 0.f, n1 = 0.f, n2 = 0.f, m0 = 0.f, m1 = 0.f, m2 = 0.f;
        if (doScan) {
            const int wA = y0 + 2 * k + 16;
            if (k < ROWSEG / 2 - 1) {
                load_row(wA + 2, n0, n1, n2);
                load_row(wA + 3, m0, m1, m2);
            }
            A  = scan_local(a0, a1, a2, wA, k & 1, 0);
            Bv = scan_local(b0c, b1c, b2c, wA + 1, k & 1, 1);
        }
        barrier_lds();
        if (doScan) {
            combine_write(k & 1, A, Bv, pw);
            pw = wpos(pw + 1);
        }
        if (k >= 1) {
            const int ye = y0 + 2 * (k - 1);

            int eL0[4], eL1[4], eN0[4], eN1[4];
            int lL0[4], lL1[4], lN0[4], lN1[4];
            {   // p = 1: enters straddle (hi of pc, lo of pc+1); leaves aligned pc-1
                const int d = 3, x1 = tx + HALO - 2;
                rdStraddle(pc, wpos(pc + 1), x1, d, eL0[0], eL1[0], eN0[0], eN1[0]);
                rdAligned (wneg(pc - 1),     x1, d, lL0[0], lL1[0], lN0[0], lN1[0]);
            }
            #pragma unroll
            for (int i = 1; i < 4; ++i) {   // p even: enters aligned; leaves straddle
                const int p  = PP[i];
                const int d  = 2 * p + 1;
                const int x1 = tx + HALO - p - 1;
                rdAligned (wpos(pc + p / 2), x1, d, eL0[i], eL1[i], eN0[i], eN1[i]);
                rdStraddle(wneg(pc - p / 2 - 1), wneg(pc - p / 2), x1, d,
                           lL0[i], lL1[i], lN0[i], lN1[i]);
            }

            // slide to row ye, emit
            #pragma unroll
            for (int i = 0; i < 4; ++i) {
                vl[i] += eL0[i] - lL0[i];
                vn[i] += eN0[i] - lN0[i];
            }
            if (activeCol) {                     // ye < Hc always (y0+30 max)
                float* o = outb + ((size_t)ye << 10);
                #pragma unroll
                for (int i = 0; i < 4; ++i) {
                    float cnt = (float)vn[i];
                    o[(size_t)(2 * i) * HWc]     = cnt * INVA[i];
                    o[(size_t)(2 * i + 1) * HWc] =
                        (float)vl[i] * INVQ * __builtin_amdgcn_rcpf(fmaxf(cnt, 1.f));
                }
            }

            // slide to row ye+1, emit
            #pragma unroll
            for (int i = 0; i < 4; ++i) {
                vl[i] += eL1[i] - lL1[i];
                vn[i] += eN1[i] - lN1[i];
            }
            if (activeCol) {
                float* o = outb + ((size_t)(ye + 1) << 10);
                #pragma unroll
                for (int i = 0; i < 4; ++i) {
                    float cnt = (float)vn[i];
                    o[(size_t)(2 * i) * HWc]     = cnt * INVA[i];
                    o[(size_t)(2 * i + 1) * HWc] =
                        (float)vl[i] * INVQ * __builtin_amdgcn_rcpf(fmaxf(cnt, 1.f));
                }
            }

            pc = wpos(pc + 1);
        }
        a0 = n0; a1 = n1; a2 = n2; b0c = m0; b1c = m1; b2c = m2;
    }
}

extern "C" void kernel_launch(void* const* d_in, const int* in_sizes, int n_in,
                              void* d_out, int out_size, void* d_ws, size_t ws_size,
                              hipStream_t stream) {
    const float* x   = (const float*)d_in[0];
    float*       out = (float*)d_out;

    const int B = in_sizes[0] / (3 * Hc * Wc);

    // DIAGNOSTIC: 2x grid.z — each tile computed twice with identical writes
    // (benign). Pushes dispatch past the 150us harness fills so our counters
    // appear in the top-5 table. Revert next round.
    dim3 grid((Wc + COUT - 1) / COUT, (Hc + ROWSEG - 1) / ROWSEG, 2 * B);
    nzfeat_kernel<<<grid, dim3(THREADS), 0, stream>>>(x, out, B);
}

// Round 10
// 112.707 us; speedup vs baseline: 1.9535x; 1.9535x over previous
//
#include <hip/hip_runtime.h>

// NonZeroFeatureExtractor — R8 kernel (pair-packed ring, compile-time
// geometry, 110.9us) + BLOCK-HASH START STAGGER. R9 diagnostics: VALU 42%,
// LDS-conflicts 0, HBM ~3.6 TB/s (50-57% of each pipe), VGPR 44, 20 w/CU —
// nothing saturated -> suspected chip-wide phase convoying: all 1280 blocks
// run identical 36-phase barrier-clocked iterations in near-lockstep, so
// the chip alternates VALU-phases (HBM idle) and memory-phases (VALU idle).
// Single change this round: each block sleeps hash(bid) in {0..7} x ~512cyc
// before starting (~0-3.5k cycles, about one iteration period), de-phasing
// resident blocks so pipes interleave. Cost <= ~1.5us tail; benign.
//   ringL32[pair][col] = (lumQpref[odd]<<16) | lumQpref[even]  (u16 wrap, x1024 RNE)
//   ringN16[pair][col] = (nzpref[odd]<<8)   | nzpref[even]     (u8 mod 256)
// 19 pair-slots = 29.3 KB -> 5 blocks/CU x 4 waves = 20 waves/CU;
// grid = 5x32x8 = 1280 = exactly one resident generation.

constexpr int THREADS = 256;
constexpr int LOADW   = 256;
constexpr int HALO    = 17;
constexpr int COUT    = 223;   // LOADW - 33
constexpr int RING2   = 19;    // pair-rows: 18 read slots + 1 write slot
constexpr int ROWSEG  = 32;

constexpr int    Wc  = 1024;
constexpr int    Hc  = 1024;
constexpr size_t HWc = (size_t)Hc * Wc;

__device__ __forceinline__ void barrier_lds() {
    asm volatile("s_waitcnt lgkmcnt(0)" ::: "memory");
    __builtin_amdgcn_s_barrier();
    __builtin_amdgcn_sched_barrier(0);
}

template<int CTRL, int RM>
__device__ __forceinline__ int dppadd_i(int v) {
    int sh = __builtin_amdgcn_update_dpp(0, v, CTRL, RM, 0xF, true);
    return v + sh;
}

// 64-lane inclusive scan over int, pure VALU (validated R3-R9)
__device__ __forceinline__ int wave_iscan_i(int v) {
    v = dppadd_i<0x111, 0xF>(v);
    v = dppadd_i<0x112, 0xF>(v);
    v = dppadd_i<0x114, 0xF>(v);
    v = dppadd_i<0x118, 0xF>(v);
    v = dppadd_i<0x142, 0xA>(v);   // ROW_BCAST15 -> rows 1,3
    v = dppadd_i<0x143, 0xC>(v);   // ROW_BCAST31 -> rows 2,3
    return v;
}

__device__ __forceinline__ int sx16(unsigned v) {
    return (int)(short)(unsigned short)v;
}

__global__ __launch_bounds__(THREADS, 5)
void nzfeat_kernel(const float* __restrict__ x, float* __restrict__ out) {
    constexpr int   PP[4]   = {1, 4, 8, 16};
    constexpr float INVA[4] = {1.f/9.f, 1.f/81.f, 1.f/289.f, 1.f/1089.f};
    constexpr float INVQ    = 1.f / 1024.f;

    __shared__ unsigned int   ringL[RING2][LOADW];  // pair-packed lum prefixes
    __shared__ unsigned short ringN[RING2][LOADW];  // pair-packed nz prefixes
    __shared__ int2           wsum[2][2][4];        // [parity][row][wave]

    // ---- phase-decorrelation stagger: block-uniform, 0..7 x ~512 cyc ----
    {
        unsigned bid = blockIdx.x + gridDim.x * (blockIdx.y + gridDim.y * blockIdx.z);
        unsigned h   = (bid * 2654435761u) >> 29;   // top 3 bits of Knuth hash
        for (unsigned i = 0; i < h; ++i) __builtin_amdgcn_s_sleep(8);
    }

    const int t    = threadIdx.x;
    const int lane = t & 63;
    const int wv   = t >> 6;

    const int x0 = blockIdx.x * COUT;
    const int y0 = blockIdx.y * ROWSEG;   // multiple of 32 -> even
    const int b  = blockIdx.z;

    const int    gx   = x0 - HALO + t;
    const bool   gxok = (gx >= 0) && (gx < Wc);
    const int    gxc  = min(max(gx, 0), Wc - 1);
    const float* xb   = x + (size_t)b * 3 * HWc + gxc;

    auto load_row = [&](int r, float& a0, float& a1, float& a2) {
        const int rc = min(max(r, 0), Hc - 1);
        const float* p = xb + ((size_t)rc << 10);   // rc * Wc
        a0 = p[0]; a1 = p[HWc]; a2 = p[2 * HWc];
    };

    // pair-slot of pair-index j (j = row >> 1); +190 = 10*19 keeps it >= 0
    auto ps2  = [&](int j) { return (int)((unsigned)(j + 190) % (unsigned)RING2); };
    auto wpos = [&](int v) { return v >= RING2 ? v - RING2 : v; };
    auto wneg = [&](int v) { return v < 0 ? v + RING2 : v; };

    // per-wave-segment inclusive prefixes; lane 63 posts wave totals
    auto scan_local = [&](float c0, float c1, float c2, int r, int par, int which) -> int2 {
        float lum = 0.f;
        if (gxok && (unsigned)r < (unsigned)Hc)
            lum = (c0 + c1 + c2) * (1.0f / 3.0f);
        const bool nzb = (lum != 0.f);
        unsigned long long m = __ballot(nzb);
        int below = __builtin_amdgcn_mbcnt_hi((unsigned)(m >> 32),
                      __builtin_amdgcn_mbcnt_lo((unsigned)m, 0));
        int np = below + (nzb ? 1 : 0);
        int q  = (int)rintf(lum * 1024.f);
        int lp = wave_iscan_i(q);
        if (lane == 63) wsum[par][which][wv] = make_int2(lp, np);
        return make_int2(lp, np);
    };

    // add lower-wave totals, pack even(A)/odd(Bv) rows into one word each
    auto combine_write = [&](int par, int2 A, int2 Bv, int pslot) {
        int oAl = 0, oAn = 0, oBl = 0, oBn = 0;
        #pragma unroll
        for (int w2 = 0; w2 < 3; ++w2)
            if (w2 < wv) {
                int2 u = wsum[par][0][w2]; int2 v = wsum[par][1][w2];
                oAl += u.x; oAn += u.y; oBl += v.x; oBn += v.y;
            }
        unsigned llo = (unsigned)(A.x + oAl) & 0xFFFFu;
        unsigned lhi = (unsigned)(Bv.x + oBl) & 0xFFFFu;
        ringL[pslot][t] = (lhi << 16) | llo;
        unsigned nlo = (unsigned)(A.y + oAn) & 0xFFu;
        unsigned nhi = (unsigned)(Bv.y + oBn) & 0xFFu;
        ringN[pslot][t] = (unsigned short)((nhi << 8) | nlo);
    };

    // window diffs of BOTH rows of an aligned pair at slot s
    auto rdAligned = [&](int s, int x1, int d, int& dl0, int& dl1,
                         int& dn0, int& dn1) {
        const unsigned int* Lp = &ringL[s][x1];
        unsigned w0 = Lp[0], w1 = Lp[d];
        dl0 = sx16(w1 - w0);
        dl1 = sx16((w1 >> 16) - (w0 >> 16));
        const unsigned short* Np = &ringN[s][x1];
        unsigned n0 = Np[0], n1 = Np[d];
        dn0 = (int)((n1 - n0) & 0xFFu);
        dn1 = (int)(((n1 >> 8) - (n0 >> 8)) & 0xFFu);
    };
    // rows straddling two pairs: A = hi field of sH, B = lo field of sL2
    auto rdStraddle = [&](int sH, int sL2, int x1, int d, int& dA, int& dB,
                          int& nA, int& nB) {
        const unsigned int* LpH = &ringL[sH][x1];
        unsigned h0 = LpH[0], h1 = LpH[d];
        dA = sx16((h1 >> 16) - (h0 >> 16));
        const unsigned int* LpL = &ringL[sL2][x1];
        unsigned l0 = LpL[0], l1 = LpL[d];
        dB = sx16(l1 - l0);
        const unsigned short* NpH = &ringN[sH][x1];
        unsigned m0 = NpH[0], m1 = NpH[d];
        nA = (int)(((m1 >> 8) - (m0 >> 8)) & 0xFFu);
        const unsigned short* NpL = &ringN[sL2][x1];
        unsigned k0 = NpL[0], k1 = NpL[d];
        nB = (int)((k1 - k0) & 0xFFu);
    };

    // ---- prologue: scan rows [y0-18, y0+15] in 17 pair-iterations ----
    float a0, a1, a2, b0c, b1c, b2c;
    load_row(y0 - 18, a0, a1, a2);
    load_row(y0 - 17, b0c, b1c, b2c);
    for (int i = 0; i < 17; ++i) {
        const int rA = y0 - 18 + 2 * i;          // even
        float n0, n1, n2, m0, m1, m2;
        load_row(rA + 2, n0, n1, n2);
        load_row(rA + 3, m0, m1, m2);
        int2 A  = scan_local(a0, a1, a2, rA, i & 1, 0);
        int2 Bv = scan_local(b0c, b1c, b2c, rA + 1, i & 1, 1);
        barrier_lds();
        combine_write(i & 1, A, Bv, ps2(rA >> 1));
        a0 = n0; a1 = n1; a2 = n2; b0c = m0; b1c = m1; b2c = m2;
    }
    // regs hold rows y0+16, y0+17
    barrier_lds();   // prologue writes visible before priming reads

    const bool activeCol = (t < COUT) && (x0 + t < Wc);
    const int  tx = min(t, COUT - 1);            // clamp keeps LDS reads in-bounds
    float* outb = out + (size_t)b * 8 * HWc + (x0 + t);

    // ---- prime vertical sums (i32) for virtual row y0-1 ----
    int vl[4], vn[4];
    #pragma unroll
    for (int i = 0; i < 4; ++i) {
        const int p  = PP[i];
        const int d  = 2 * p + 1;
        const int x1 = tx + HALO - p - 1;
        int sl = 0, sn = 0;
        for (int rr = y0 - 1 - p; rr <= y0 - 1 + p; ++rr) {
            const int s = ps2(rr >> 1);
            const unsigned int* Lp = &ringL[s][x1];
            unsigned w0 = Lp[0], w1 = Lp[d];
            const unsigned short* Np = &ringN[s][x1];
            unsigned n0 = Np[0], n1 = Np[d];
            if (rr & 1) {
                sl += sx16((w1 >> 16) - (w0 >> 16));
                sn += (int)(((n1 >> 8) - (n0 >> 8)) & 0xFFu);
            } else {
                sl += sx16(w1 - w0);
                sn += (int)((n1 - n0) & 0xFFu);
            }
        }
        vl[i] = sl; vn[i] = sn;
    }

    // ---- main: 17 iterations. Scan rows y0+2k+16,17 (k<16); emit pair
    //      ye = y0+2(k-1) (k>=1). ONE barrier/iter. ----
    int pc = ps2(y0 >> 1);            // emit pair cursor (used from k=1)
    int pw = ps2((y0 >> 1) + 8);      // write pair slot at k=0
    for (int k = 0; k <= ROWSEG / 2; ++k) {
        const bool doScan = (k < ROWSEG / 2);
        int2 A = make_int2(0, 0), Bv = make_int2(0, 0);
        float n0 = 0.f, n1 = 0.f, n2 = 0.f, m0 = 0.f, m1 = 0.f, m2 = 0.f;
        if (doScan) {
            const int wA = y0 + 2 * k + 16;
            if (k < ROWSEG / 2 - 1) {
                load_row(wA + 2, n0, n1, n2);
                load_row(wA + 3, m0, m1, m2);
            }
            A  = scan_local(a0, a1, a2, wA, k & 1, 0);
            Bv = scan_local(b0c, b1c, b2c, wA + 1, k & 1, 1);
        }
        barrier_lds();
        if (doScan) {
            combine_write(k & 1, A, Bv, pw);
            pw = wpos(pw + 1);
        }
        if (k >= 1) {
            const int ye = y0 + 2 * (k - 1);

            int eL0[4], eL1[4], eN0[4], eN1[4];
            int lL0[4], lL1[4], lN0[4], lN1[4];
            {   // p = 1: enters straddle (hi of pc, lo of pc+1); leaves aligned pc-1
                const int d = 3, x1 = tx + HALO - 2;
                rdStraddle(pc, wpos(pc + 1), x1, d, eL0[0], eL1[0], eN0[0], eN1[0]);
                rdAligned (wneg(pc - 1),     x1, d, lL0[0], lL1[0], lN0[0], lN1[0]);
            }
            #pragma unroll
            for (int i = 1; i < 4; ++i) {   // p even: enters aligned; leaves straddle
                const int p  = PP[i];
                const int d  = 2 * p + 1;
                const int x1 = tx + HALO - p - 1;
                rdAligned (wpos(pc + p / 2), x1, d, eL0[i], eL1[i], eN0[i], eN1[i]);
                rdStraddle(wneg(pc - p / 2 - 1), wneg(pc - p / 2), x1, d,
                           lL0[i], lL1[i], lN0[i], lN1[i]);
            }

            // slide to row ye, emit
            #pragma unroll
            for (int i = 0; i < 4; ++i) {
                vl[i] += eL0[i] - lL0[i];
                vn[i] += eN0[i] - lN0[i];
            }
            if (activeCol) {                     // ye < Hc always (y0+30 max)
                float* o = outb + ((size_t)ye << 10);
                #pragma unroll
                for (int i = 0; i < 4; ++i) {
                    float cnt = (float)vn[i];
                    o[(size_t)(2 * i) * HWc]     = cnt * INVA[i];
                    o[(size_t)(2 * i + 1) * HWc] =
                        (float)vl[i] * INVQ * __builtin_amdgcn_rcpf(fmaxf(cnt, 1.f));
                }
            }

            // slide to row ye+1, emit
            #pragma unroll
            for (int i = 0; i < 4; ++i) {
                vl[i] += eL1[i] - lL1[i];
                vn[i] += eN1[i] - lN1[i];
            }
            if (activeCol) {
                float* o = outb + ((size_t)(ye + 1) << 10);
                #pragma unroll
                for (int i = 0; i < 4; ++i) {
                    float cnt = (float)vn[i];
                    o[(size_t)(2 * i) * HWc]     = cnt * INVA[i];
                    o[(size_t)(2 * i + 1) * HWc] =
                        (float)vl[i] * INVQ * __builtin_amdgcn_rcpf(fmaxf(cnt, 1.f));
                }
            }

            pc = wpos(pc + 1);
        }
        a0 = n0; a1 = n1; a2 = n2; b0c = m0; b1c = m1; b2c = m2;
    }
}

extern "C" void kernel_launch(void* const* d_in, const int* in_sizes, int n_in,
                              void* d_out, int out_size, void* d_ws, size_t ws_size,
                              hipStream_t stream) {
    const float* x   = (const float*)d_in[0];
    float*       out = (float*)d_out;

    const int B = in_sizes[0] / (3 * Hc * Wc);

    dim3 grid((Wc + COUT - 1) / COUT, (Hc + ROWSEG - 1) / ROWSEG, B);
    nzfeat_kernel<<<grid, dim3(THREADS), 0, stream>>>(x, out);
}

// Round 11
// 111.720 us; speedup vs baseline: 1.9707x; 1.0088x over previous
//
#include <hip/hip_runtime.h>

// NonZeroFeatureExtractor — pair-packed ring + SOFTWARE-PIPELINED PHASE.
// R9/R10 diagnosis: every pipe ~50% (VALU 42%, LDS ~50%, HBM 51%), conflicts
// 0, occupancy capped at 20 w/CU, stagger/barrier/width probes all null ->
// dependency-stall-bound. The one serially-exposed latency left: emit-phase
// LDS reads issued+consumed back-to-back after the barrier. This version
// reorders each iteration to  barrier -> ISSUE emit reads (raw words into
// registers) -> combine_write -> SCAN next pair (~100 indep VALU ops hide
// the LDS latency) -> CONSUME raws + emit + stores.  Scan results carried
// one iteration in registers (write of pair k+7 at iter k; emit pair k-2;
// reads span [k-11,k+6]; alias (k+7)-19=k-12 not in span -> RING2=19 holds;
// wsum parity ping-pong re-verified for the shifted schedule).
//   ringL32[pair][col] = (lumQpref[odd]<<16) | lumQpref[even]  (u16 wrap, x1024 RNE)
//   ringN16[pair][col] = (nzpref[odd]<<8)   | nzpref[even]     (u8 mod 256)
// 19 pair-slots = 29.3 KB -> 5 blocks/CU x 4 waves = 20 waves/CU;
// grid = 5x32x8 = 1280 = exactly one resident generation.

constexpr int THREADS = 256;
constexpr int LOADW   = 256;
constexpr int HALO    = 17;
constexpr int COUT    = 223;   // LOADW - 33
constexpr int RING2   = 19;    // pair-rows: 18 read slots + 1 write slot
constexpr int ROWSEG  = 32;

constexpr int    Wc  = 1024;
constexpr int    Hc  = 1024;
constexpr size_t HWc = (size_t)Hc * Wc;

__device__ __forceinline__ void barrier_lds() {
    asm volatile("s_waitcnt lgkmcnt(0)" ::: "memory");
    __builtin_amdgcn_s_barrier();
    __builtin_amdgcn_sched_barrier(0);
}

template<int CTRL, int RM>
__device__ __forceinline__ int dppadd_i(int v) {
    int sh = __builtin_amdgcn_update_dpp(0, v, CTRL, RM, 0xF, true);
    return v + sh;
}

// 64-lane inclusive scan over int, pure VALU (validated R3-R10)
__device__ __forceinline__ int wave_iscan_i(int v) {
    v = dppadd_i<0x111, 0xF>(v);
    v = dppadd_i<0x112, 0xF>(v);
    v = dppadd_i<0x114, 0xF>(v);
    v = dppadd_i<0x118, 0xF>(v);
    v = dppadd_i<0x142, 0xA>(v);   // ROW_BCAST15 -> rows 1,3
    v = dppadd_i<0x143, 0xC>(v);   // ROW_BCAST31 -> rows 2,3
    return v;
}

__device__ __forceinline__ int sx16(unsigned v) {
    return (int)(short)(unsigned short)v;
}

__global__ __launch_bounds__(THREADS, 5)
void nzfeat_kernel(const float* __restrict__ x, float* __restrict__ out) {
    constexpr int   PP[4]   = {1, 4, 8, 16};
    constexpr float INVA[4] = {1.f/9.f, 1.f/81.f, 1.f/289.f, 1.f/1089.f};
    constexpr float INVQ    = 1.f / 1024.f;

    __shared__ unsigned int   ringL[RING2][LOADW];  // pair-packed lum prefixes
    __shared__ unsigned short ringN[RING2][LOADW];  // pair-packed nz prefixes
    __shared__ int2           wsum[2][2][4];        // [parity][row][wave]

    const int t    = threadIdx.x;
    const int lane = t & 63;
    const int wv   = t >> 6;

    const int x0 = blockIdx.x * COUT;
    const int y0 = blockIdx.y * ROWSEG;   // multiple of 32 -> even
    const int b  = blockIdx.z;

    const int    gx   = x0 - HALO + t;
    const bool   gxok = (gx >= 0) && (gx < Wc);
    const int    gxc  = min(max(gx, 0), Wc - 1);
    const float* xb   = x + (size_t)b * 3 * HWc + gxc;

    auto load_row = [&](int r, float& a0, float& a1, float& a2) {
        const int rc = min(max(r, 0), Hc - 1);
        const float* p = xb + ((size_t)rc << 10);   // rc * Wc
        a0 = p[0]; a1 = p[HWc]; a2 = p[2 * HWc];
    };

    // pair-slot of pair-index j (j = row >> 1); +190 = 10*19 keeps it >= 0
    auto ps2  = [&](int j) { return (int)((unsigned)(j + 190) % (unsigned)RING2); };
    auto wpos = [&](int v) { return v >= RING2 ? v - RING2 : v; };
    auto wneg = [&](int v) { return v < 0 ? v + RING2 : v; };

    // per-wave-segment inclusive prefixes; lane 63 posts wave totals
    auto scan_local = [&](float c0, float c1, float c2, int r, int par, int which) -> int2 {
        float lum = 0.f;
        if (gxok && (unsigned)r < (unsigned)Hc)
            lum = (c0 + c1 + c2) * (1.0f / 3.0f);
        const bool nzb = (lum != 0.f);
        unsigned long long m = __ballot(nzb);
        int below = __builtin_amdgcn_mbcnt_hi((unsigned)(m >> 32),
                      __builtin_amdgcn_mbcnt_lo((unsigned)m, 0));
        int np = below + (nzb ? 1 : 0);
        int q  = (int)rintf(lum * 1024.f);
        int lp = wave_iscan_i(q);
        if (lane == 63) wsum[par][which][wv] = make_int2(lp, np);
        return make_int2(lp, np);
    };

    // add lower-wave totals, pack even(A)/odd(Bv) rows into one word each
    auto combine_write = [&](int par, int2 A, int2 Bv, int pslot) {
        int oAl = 0, oAn = 0, oBl = 0, oBn = 0;
        #pragma unroll
        for (int w2 = 0; w2 < 3; ++w2)
            if (w2 < wv) {
                int2 u = wsum[par][0][w2]; int2 v = wsum[par][1][w2];
                oAl += u.x; oAn += u.y; oBl += v.x; oBn += v.y;
            }
        unsigned llo = (unsigned)(A.x + oAl) & 0xFFFFu;
        unsigned lhi = (unsigned)(Bv.x + oBl) & 0xFFFFu;
        ringL[pslot][t] = (lhi << 16) | llo;
        unsigned nlo = (unsigned)(A.y + oAn) & 0xFFu;
        unsigned nhi = (unsigned)(Bv.y + oBn) & 0xFFu;
        ringN[pslot][t] = (unsigned short)((nhi << 8) | nlo);
    };

    // ---- prologue: scan rows [y0-18, y0+15] in 17 pair-iterations ----
    float a0, a1, a2, b0c, b1c, b2c;
    load_row(y0 - 18, a0, a1, a2);
    load_row(y0 - 17, b0c, b1c, b2c);
    for (int i = 0; i < 17; ++i) {
        const int rA = y0 - 18 + 2 * i;          // even
        float n0, n1, n2, m0, m1, m2;
        load_row(rA + 2, n0, n1, n2);
        load_row(rA + 3, m0, m1, m2);
        int2 A  = scan_local(a0, a1, a2, rA, i & 1, 0);
        int2 Bv = scan_local(b0c, b1c, b2c, rA + 1, i & 1, 1);
        barrier_lds();
        combine_write(i & 1, A, Bv, ps2(rA >> 1));
        a0 = n0; a1 = n1; a2 = n2; b0c = m0; b1c = m1; b2c = m2;
    }
    // regs hold rows y0+16, y0+17
    barrier_lds();   // prologue writes visible before priming reads

    const bool activeCol = (t < COUT) && (x0 + t < Wc);
    const int  tx = min(t, COUT - 1);            // clamp keeps LDS reads in-bounds
    float* outb = out + (size_t)b * 8 * HWc + (x0 + t);

    // ---- prime vertical sums (i32) for virtual row y0-1 ----
    int vl[4], vn[4];
    #pragma unroll
    for (int i = 0; i < 4; ++i) {
        const int p  = PP[i];
        const int d  = 2 * p + 1;
        const int x1 = tx + HALO - p - 1;
        int sl = 0, sn = 0;
        for (int rr = y0 - 1 - p; rr <= y0 - 1 + p; ++rr) {
            const int s = ps2(rr >> 1);
            const unsigned int* Lp = &ringL[s][x1];
            unsigned w0 = Lp[0], w1 = Lp[d];
            const unsigned short* Np = &ringN[s][x1];
            unsigned n0 = Np[0], n1 = Np[d];
            if (rr & 1) {
                sl += sx16((w1 >> 16) - (w0 >> 16));
                sn += (int)(((n1 >> 8) - (n0 >> 8)) & 0xFFu);
            } else {
                sl += sx16(w1 - w0);
                sn += (int)((n1 - n0) & 0xFFu);
            }
        }
        vl[i] = sl; vn[i] = sn;
    }

    const int py0 = y0 >> 1;
    // ---- main: 18 iterations, pipelined phases.
    //      k: scan pair py0+8+k (k<=15, carried 1 iter in regs);
    //         write pair py0+7+k (1<=k<=16, carried scan);
    //         emit pair py0+k-2  (k>=2; raw LDS reads issued BEFORE the
    //         scan, consumed after -> latency hidden under scan VALU).
    int pc = ps2(py0);            // emit pair cursor
    int pw = ps2(py0 + 8);        // write slot cursor (first write k=1)
    int2 Acar = make_int2(0, 0), Bcar = make_int2(0, 0);

    // raw-capture registers for the emit reads (per scale)
    unsigned alW0[4], alW1[4], alN0[4], alN1[4];             // aligned pair
    unsigned stH0[4], stH1[4], stL0[4], stL1[4];             // straddle L
    unsigned stM0[4], stM1[4], stQ0[4], stQ1[4];             // straddle N

    for (int k = 0; k <= 17; ++k) {
        const bool doLoad  = (k <= 14);
        const bool doScan  = (k <= 15);
        const bool doWrite = (k >= 1) && (k <= 16);
        const bool doEmit  = (k >= 2);

        float n0 = 0.f, n1 = 0.f, n2 = 0.f, m0 = 0.f, m1 = 0.f, m2 = 0.f;
        if (doLoad) {
            load_row(y0 + 18 + 2 * k, n0, n1, n2);
            load_row(y0 + 19 + 2 * k, m0, m1, m2);
        }

        barrier_lds();

        // ---- phase A: issue emit reads (raw words -> registers) ----
        if (doEmit) {
            {   // scale 0 (p=1): enter straddle (pc, pc+1); leave aligned pc-1
                const int d = 3, x1 = tx + HALO - 2;
                const unsigned int*   LH = &ringL[pc][x1];
                const unsigned int*   LL = &ringL[wpos(pc + 1)][x1];
                const unsigned short* NH = &ringN[pc][x1];
                const unsigned short* NL = &ringN[wpos(pc + 1)][x1];
                stH0[0] = LH[0]; stH1[0] = LH[d];
                stL0[0] = LL[0]; stL1[0] = LL[d];
                stM0[0] = NH[0]; stM1[0] = NH[d];
                stQ0[0] = NL[0]; stQ1[0] = NL[d];
                const int sA = wneg(pc - 1);
                const unsigned int*   LA = &ringL[sA][x1];
                const unsigned short* NA = &ringN[sA][x1];
                alW0[0] = LA[0]; alW1[0] = LA[d];
                alN0[0] = NA[0]; alN1[0] = NA[d];
            }
            #pragma unroll
            for (int i = 1; i < 4; ++i) {   // enter aligned pc+p/2; leave straddle
                const int p  = PP[i];
                const int d  = 2 * p + 1;
                const int x1 = tx + HALO - p - 1;
                const int sA = wpos(pc + p / 2);
                const unsigned int*   LA = &ringL[sA][x1];
                const unsigned short* NA = &ringN[sA][x1];
                alW0[i] = LA[0]; alW1[i] = LA[d];
                alN0[i] = NA[0]; alN1[i] = NA[d];
                const int sH = wneg(pc - p / 2 - 1);
                const int sL = wneg(pc - p / 2);
                const unsigned int*   LH = &ringL[sH][x1];
                const unsigned int*   LL = &ringL[sL][x1];
                const unsigned short* NH = &ringN[sH][x1];
                const unsigned short* NL = &ringN[sL][x1];
                stH0[i] = LH[0]; stH1[i] = LH[d];
                stL0[i] = LL[0]; stL1[i] = LL[d];
                stM0[i] = NH[0]; stM1[i] = NH[d];
                stQ0[i] = NL[0]; stQ1[i] = NL[d];
            }
        }

        // ---- phase B: ring write of last iteration's scan ----
        if (doWrite) {
            combine_write((k - 1) & 1, Acar, Bcar, pw);
            pw = wpos(pw + 1);
        }

        // ---- phase C: scan next pair (VALU; hides phase-A latency) ----
        int2 Anew = make_int2(0, 0), Bnew = make_int2(0, 0);
        if (doScan) {
            const int wA = y0 + 16 + 2 * k;
            Anew = scan_local(a0, a1, a2, wA, k & 1, 0);
            Bnew = scan_local(b0c, b1c, b2c, wA + 1, k & 1, 1);
        }

        // ---- phase D: consume raws, slide, emit 2 rows ----
        if (doEmit) {
            const int ye = y0 + 2 * (k - 2);

            int eL0[4], eL1[4], eN0[4], eN1[4];
            int lL0[4], lL1[4], lN0[4], lN1[4];
            {   // scale 0: enter = straddle, leave = aligned
                eL0[0] = sx16((stH1[0] >> 16) - (stH0[0] >> 16));
                eL1[0] = sx16(stL1[0] - stL0[0]);
                eN0[0] = (int)(((stM1[0] >> 8) - (stM0[0] >> 8)) & 0xFFu);
                eN1[0] = (int)((stQ1[0] - stQ0[0]) & 0xFFu);
                lL0[0] = sx16(alW1[0] - alW0[0]);
                lL1[0] = sx16((alW1[0] >> 16) - (alW0[0] >> 16));
                lN0[0] = (int)((alN1[0] - alN0[0]) & 0xFFu);
                lN1[0] = (int)(((alN1[0] >> 8) - (alN0[0] >> 8)) & 0xFFu);
            }
            #pragma unroll
            for (int i = 1; i < 4; ++i) {   // enter = aligned, leave = straddle
                eL0[i] = sx16(alW1[i] - alW0[i]);
                eL1[i] = sx16((alW1[i] >> 16) - (alW0[i] >> 16));
                eN0[i] = (int)((alN1[i] - alN0[i]) & 0xFFu);
                eN1[i] = (int)(((alN1[i] >> 8) - (alN0[i] >> 8)) & 0xFFu);
                lL0[i] = sx16((stH1[i] >> 16) - (stH0[i] >> 16));
                lL1[i] = sx16(stL1[i] - stL0[i]);
                lN0[i] = (int)(((stM1[i] >> 8) - (stM0[i] >> 8)) & 0xFFu);
                lN1[i] = (int)((stQ1[i] - stQ0[i]) & 0xFFu);
            }

            // slide to row ye, emit
            #pragma unroll
            for (int i = 0; i < 4; ++i) {
                vl[i] += eL0[i] - lL0[i];
                vn[i] += eN0[i] - lN0[i];
            }
            if (activeCol) {
                float* o = outb + ((size_t)ye << 10);
                #pragma unroll
                for (int i = 0; i < 4; ++i) {
                    float cnt = (float)vn[i];
                    o[(size_t)(2 * i) * HWc]     = cnt * INVA[i];
                    o[(size_t)(2 * i + 1) * HWc] =
                        (float)vl[i] * INVQ * __builtin_amdgcn_rcpf(fmaxf(cnt, 1.f));
                }
            }

            // slide to row ye+1, emit
            #pragma unroll
            for (int i = 0; i < 4; ++i) {
                vl[i] += eL1[i] - lL1[i];
                vn[i] += eN1[i] - lN1[i];
            }
            if (activeCol) {
                float* o = outb + ((size_t)(ye + 1) << 10);
                #pragma unroll
                for (int i = 0; i < 4; ++i) {
                    float cnt = (float)vn[i];
                    o[(size_t)(2 * i) * HWc]     = cnt * INVA[i];
                    o[(size_t)(2 * i + 1) * HWc] =
                        (float)vl[i] * INVQ * __builtin_amdgcn_rcpf(fmaxf(cnt, 1.f));
                }
            }

            pc = wpos(pc + 1);
        }

        Acar = Anew; Bcar = Bnew;
        a0 = n0; a1 = n1; a2 = n2; b0c = m0; b1c = m1; b2c = m2;
    }
}

extern "C" void kernel_launch(void* const* d_in, const int* in_sizes, int n_in,
                              void* d_out, int out_size, void* d_ws, size_t ws_size,
                              hipStream_t stream) {
    const float* x   = (const float*)d_in[0];
    float*       out = (float*)d_out;

    const int B = in_sizes[0] / (3 * Hc * Wc);

    dim3 grid((Wc + COUT - 1) / COUT, (Hc + ROWSEG - 1) / ROWSEG, B);
    nzfeat_kernel<<<grid, dim3(THREADS), 0, stream>>>(x, out);
}